// Round 1
// baseline (15741.431 us; speedup 1.0000x reference)
//
#include <hip/hip_runtime.h>
#include <math.h>

// Sizes fixed by the problem
#define BATCH 128
#define TT 512      // time steps
#define CIN 512
#define HID 256
#define GG 1024     // 4*HID

__device__ __forceinline__ float sigf(float x) { return 1.f / (1.f + __expf(-x)); }
__device__ __forceinline__ float tanhf_(float x) {
    float a = fabsf(x);
    float e = __expf(-2.f * a);
    float r = (1.f - e) / (1.f + e);
    return copysignf(r, x);
}

// C[b][m,n] = relu( sum_k W[m,k] * X[b][k,n] + bias[m] )
// grid: (N/64, M/64, B), block 256, 4x4 per thread
__global__ __launch_bounds__(256) void wgemm_bias_relu(
    const float* __restrict__ W, const float* __restrict__ X,
    const float* __restrict__ bias, float* __restrict__ Y,
    int M, int N, int K)
{
    const int b = blockIdx.z;
    const float* Xb = X + (size_t)b * K * N;
    float* Yb = Y + (size_t)b * M * N;
    const int m0 = blockIdx.y * 64, n0 = blockIdx.x * 64;
    __shared__ float As[16][68];
    __shared__ float Bs[16][64];
    const int tid = threadIdx.x;
    const int tx = tid & 15, ty = tid >> 4;
    float acc[4][4] = {{0.f, 0.f, 0.f, 0.f}, {0.f, 0.f, 0.f, 0.f},
                       {0.f, 0.f, 0.f, 0.f}, {0.f, 0.f, 0.f, 0.f}};
    for (int k0 = 0; k0 < K; k0 += 16) {
        {
            const int m = tid >> 2, kq = (tid & 3) << 2;
            float4 a = *(const float4*)(W + (size_t)(m0 + m) * K + k0 + kq);
            As[kq + 0][m] = a.x; As[kq + 1][m] = a.y;
            As[kq + 2][m] = a.z; As[kq + 3][m] = a.w;
            const int kk = tid >> 4, n4 = (tid & 15) << 2;
            float4 xv = *(const float4*)(Xb + (size_t)(k0 + kk) * N + n0 + n4);
            *(float4*)&Bs[kk][n4] = xv;
        }
        __syncthreads();
        #pragma unroll
        for (int k = 0; k < 16; ++k) {
            const float4 a = *(const float4*)&As[k][ty << 2];
            const float4 b4 = *(const float4*)&Bs[k][tx << 2];
            const float av[4] = {a.x, a.y, a.z, a.w};
            const float bv[4] = {b4.x, b4.y, b4.z, b4.w};
            #pragma unroll
            for (int i = 0; i < 4; ++i)
                #pragma unroll
                for (int j = 0; j < 4; ++j)
                    acc[i][j] += av[i] * bv[j];
        }
        __syncthreads();
    }
    #pragma unroll
    for (int i = 0; i < 4; ++i) {
        const int m = m0 + (ty << 2) + i;
        const float bi = bias[m];
        float4 r;
        r.x = fmaxf(acc[i][0] + bi, 0.f);
        r.y = fmaxf(acc[i][1] + bi, 0.f);
        r.z = fmaxf(acc[i][2] + bi, 0.f);
        r.w = fmaxf(acc[i][3] + bi, 0.f);
        *(float4*)(Yb + (size_t)m * N + n0 + (tx << 2)) = r;
    }
}

// C[r,n] = sum_k A[r,k]*Bt[n,k] + bias1[n] + bias2[n]
// grid: (N/64, M/64), block 256, 4x4 per thread
__global__ __launch_bounds__(256) void gemm_abt_bias(
    const float* __restrict__ A, const float* __restrict__ Bt,
    const float* __restrict__ bias1, const float* __restrict__ bias2,
    float* __restrict__ C, int M, int N, int K)
{
    const int r0 = blockIdx.y * 64, n0 = blockIdx.x * 64;
    __shared__ float As[16][68];
    __shared__ float Bs[16][68];
    const int tid = threadIdx.x;
    const int tx = tid & 15, ty = tid >> 4;
    float acc[4][4] = {{0.f, 0.f, 0.f, 0.f}, {0.f, 0.f, 0.f, 0.f},
                       {0.f, 0.f, 0.f, 0.f}, {0.f, 0.f, 0.f, 0.f}};
    for (int k0 = 0; k0 < K; k0 += 16) {
        {
            const int r = tid >> 2, kq = (tid & 3) << 2;
            float4 a = *(const float4*)(A + (size_t)(r0 + r) * K + k0 + kq);
            As[kq + 0][r] = a.x; As[kq + 1][r] = a.y;
            As[kq + 2][r] = a.z; As[kq + 3][r] = a.w;
            float4 bq = *(const float4*)(Bt + (size_t)(n0 + r) * K + k0 + kq);
            Bs[kq + 0][r] = bq.x; Bs[kq + 1][r] = bq.y;
            Bs[kq + 2][r] = bq.z; Bs[kq + 3][r] = bq.w;
        }
        __syncthreads();
        #pragma unroll
        for (int k = 0; k < 16; ++k) {
            const float4 a = *(const float4*)&As[k][ty << 2];
            const float4 b4 = *(const float4*)&Bs[k][tx << 2];
            const float av[4] = {a.x, a.y, a.z, a.w};
            const float bv[4] = {b4.x, b4.y, b4.z, b4.w};
            #pragma unroll
            for (int i = 0; i < 4; ++i)
                #pragma unroll
                for (int j = 0; j < 4; ++j)
                    acc[i][j] += av[i] * bv[j];
        }
        __syncthreads();
    }
    float bb[4];
    #pragma unroll
    for (int j = 0; j < 4; ++j) {
        const int n = n0 + (tx << 2) + j;
        bb[j] = bias1[n] + bias2[n];
    }
    #pragma unroll
    for (int i = 0; i < 4; ++i) {
        const int r = r0 + (ty << 2) + i;
        float4 v;
        v.x = acc[i][0] + bb[0];
        v.y = acc[i][1] + bb[1];
        v.z = acc[i][2] + bb[2];
        v.w = acc[i][3] + bb[3];
        *(float4*)(C + (size_t)r * N + n0 + (tx << 2)) = v;
    }
}

// Forward LSTM scan. 64 blocks x 512 threads; block handles batches (2*bid, 2*bid+1).
// Thread t owns gate rows (t, t+512):
//   t in [0,256):   rows t (= i gate of j=t)     and t+512 (= g gate of j=t)
//   t in [256,512): rows t (= f gate of j=t-256) and t+512 (= o gate of j=t-256)
// i,g cross to the f/o owner via LDS; c-state lives in the f/o owner's registers.
__global__ __launch_bounds__(512) void lstm_scan(
    const float* __restrict__ xg, const float* __restrict__ whh,
    float* __restrict__ out)
{
    const int tid = threadIdx.x;
    const int b0 = blockIdx.x * 2;
    __shared__ float hsh[2][256];
    __shared__ float ish[2][256];
    __shared__ float gsh[2][256];
    if (tid < 256) { hsh[0][tid] = 0.f; hsh[1][tid] = 0.f; }
    float c0 = 0.f, c1 = 0.f;
    const float* wA = whh + (size_t)tid * 256;
    const float* wB = whh + (size_t)(tid + 512) * 256;
    const float* xgb0 = xg + (size_t)b0 * TT * GG;
    const float* xgb1 = xg + (size_t)(b0 + 1) * TT * GG;
    // prefetch step-0 xg values
    float pA0 = xgb0[tid], pB0 = xgb0[tid + 512];
    float pA1 = xgb1[tid], pB1 = xgb1[tid + 512];
    __syncthreads();
    for (int t = 0; t < TT; ++t) {
        float accA0 = pA0, accB0 = pB0, accA1 = pA1, accB1 = pB1;
        if (t < TT - 1) {  // prefetch next step (hidden behind the k-loop)
            const int o = (t + 1) * GG;
            pA0 = xgb0[o + tid]; pB0 = xgb0[o + tid + 512];
            pA1 = xgb1[o + tid]; pB1 = xgb1[o + tid + 512];
        }
        #pragma unroll 4
        for (int k = 0; k < 256; k += 4) {
            const float4 wa = *(const float4*)&wA[k];
            const float4 wb = *(const float4*)&wB[k];
            const float4 h0 = *(const float4*)&hsh[0][k];
            const float4 h1 = *(const float4*)&hsh[1][k];
            accA0 += wa.x * h0.x; accA0 += wa.y * h0.y;
            accA0 += wa.z * h0.z; accA0 += wa.w * h0.w;
            accB0 += wb.x * h0.x; accB0 += wb.y * h0.y;
            accB0 += wb.z * h0.z; accB0 += wb.w * h0.w;
            accA1 += wa.x * h1.x; accA1 += wa.y * h1.y;
            accA1 += wa.z * h1.z; accA1 += wa.w * h1.w;
            accB1 += wb.x * h1.x; accB1 += wb.y * h1.y;
            accB1 += wb.z * h1.z; accB1 += wb.w * h1.w;
        }
        if (tid < 256) {
            ish[0][tid] = accA0; ish[1][tid] = accA1;
            gsh[0][tid] = accB0; gsh[1][tid] = accB1;
        }
        __syncthreads();
        if (tid >= 256) {
            const int j = tid - 256;
            float i0 = sigf(ish[0][j]), g0 = tanhf_(gsh[0][j]);
            float f0 = sigf(accA0), o0 = sigf(accB0);
            c0 = f0 * c0 + i0 * g0;
            hsh[0][j] = o0 * tanhf_(c0);
            float i1 = sigf(ish[1][j]), g1 = tanhf_(gsh[1][j]);
            float f1 = sigf(accA1), o1 = sigf(accB1);
            c1 = f1 * c1 + i1 * g1;
            hsh[1][j] = o1 * tanhf_(c1);
        }
        __syncthreads();
    }
    if (tid < 256) {
        out[(size_t)b0 * 512 + tid] = hsh[0][tid];
        out[(size_t)(b0 + 1) * 512 + tid] = hsh[1][tid];
    }
}

// Backward-direction LSTM, last output only = FIRST step of the reversed scan
// with h=c=0: gates depend only on seq[:, T-1, :] @ w_ih_b^T + biases.
// grid 128 (one per batch), block 256 (one per hidden unit).
__global__ __launch_bounds__(256) void lstm_back_last(
    const float* __restrict__ y2, const float* __restrict__ wih,
    const float* __restrict__ bih, const float* __restrict__ bhh,
    float* __restrict__ out)
{
    const int b = blockIdx.x;
    const int t = threadIdx.x;
    __shared__ float s[256];
    s[t] = y2[(size_t)b * (HID * TT) + (TT - 1) * HID + t];
    __syncthreads();
    float acc[4];
    #pragma unroll
    for (int q = 0; q < 4; ++q) acc[q] = bih[t + q * 256] + bhh[t + q * 256];
    #pragma unroll
    for (int q = 0; q < 4; ++q) {
        const float* w = wih + (size_t)(t + q * 256) * 256;
        float a = acc[q];
        for (int k = 0; k < 256; k += 4) {
            const float4 w4 = *(const float4*)&w[k];
            const float4 h4 = *(const float4*)&s[k];
            a += w4.x * h4.x; a += w4.y * h4.y;
            a += w4.z * h4.z; a += w4.w * h4.w;
        }
        acc[q] = a;
    }
    const float i = sigf(acc[0]), f = sigf(acc[1]);
    const float g = tanhf_(acc[2]), o = sigf(acc[3]);
    (void)f;  // c_prev = 0, forget path vanishes
    const float c = i * g;
    const float h = o * tanhf_(c);
    out[(size_t)b * 512 + 256 + t] = h;
}

extern "C" void kernel_launch(void* const* d_in, const int* in_sizes, int n_in,
                              void* d_out, int out_size, void* d_ws, size_t ws_size,
                              hipStream_t stream) {
    const float* x      = (const float*)d_in[0];
    const float* w1     = (const float*)d_in[1];
    const float* b1     = (const float*)d_in[2];
    const float* w2     = (const float*)d_in[3];
    const float* b2     = (const float*)d_in[4];
    const float* w_ih_f = (const float*)d_in[5];
    const float* w_hh_f = (const float*)d_in[6];
    const float* b_ih_f = (const float*)d_in[7];
    const float* b_hh_f = (const float*)d_in[8];
    const float* w_ih_b = (const float*)d_in[9];
    // d_in[10] = w_hh_b: provably unused (only first reversed step reaches the output)
    const float* b_ih_b = (const float*)d_in[11];
    const float* b_hh_b = (const float*)d_in[12];
    float* out = (float*)d_out;

    // Workspace layout (floats):
    //   y2 : [0, 16777216)                 67.1 MB  (= seq, reshape is identity)
    //   y1 : [16777216, 33554432)          67.1 MB  (dead after conv2)
    //   xg : [16777216, 83886080)         268.4 MB  (overlays y1)
    float* ws = (float*)d_ws;
    float* y2 = ws;
    float* y1 = ws + (size_t)16777216;
    float* xg = ws + (size_t)16777216;

    // conv1: M=256, N=512, K=512
    wgemm_bias_relu<<<dim3(8, 4, BATCH), 256, 0, stream>>>(w1, x, b1, y1, HID, TT, CIN);
    // conv2: M=256, N=512, K=256
    wgemm_bias_relu<<<dim3(8, 4, BATCH), 256, 0, stream>>>(w2, y1, b2, y2, HID, TT, HID);
    // xg_f = seq @ w_ih_f^T + b_ih_f + b_hh_f : M=65536, N=1024, K=256
    gemm_abt_bias<<<dim3(16, 1024), 256, 0, stream>>>(y2, w_ih_f, b_ih_f, b_hh_f,
                                                      xg, BATCH * TT, GG, HID);
    // forward scan (writes out[:, 0:256))
    lstm_scan<<<64, 512, 0, stream>>>(xg, w_hh_f, out);
    // backward last step (writes out[:, 256:512))
    lstm_back_last<<<BATCH, 256, 0, stream>>>(y2, w_ih_b, b_ih_b, b_hh_b, out);
}

// Round 2
// 3244.152 us; speedup vs baseline: 4.8522x; 4.8522x over previous
//
#include <hip/hip_runtime.h>
#include <math.h>

// Sizes fixed by the problem
#define BATCH 128
#define TT 512      // time steps
#define CIN 512
#define HID 256
#define GG 1024     // 4*HID

typedef _Float16 half2_t __attribute__((ext_vector_type(2)));

__device__ __forceinline__ float sigf(float x) { return 1.f / (1.f + __expf(-x)); }
__device__ __forceinline__ float tanhf_(float x) {
    float a = fabsf(x);
    float e = __expf(-2.f * a);
    float r = (1.f - e) / (1.f + e);
    return copysignf(r, x);
}

// v_dot2_f32_f16: 2-way f16 dot with fp32 accumulate
__device__ __forceinline__ float fdot2_(half2_t a, half2_t b, float c) {
#if __has_builtin(__builtin_amdgcn_fdot2)
    return __builtin_amdgcn_fdot2(a, b, c, false);
#else
    return c + (float)a.x * (float)b.x + (float)a.y * (float)b.y;
#endif
}

// C[b][m,n] = relu( sum_k W[m,k] * X[b][k,n] + bias[m] )
// grid: (N/64, M/64, B), block 256, 4x4 per thread
__global__ __launch_bounds__(256) void wgemm_bias_relu(
    const float* __restrict__ W, const float* __restrict__ X,
    const float* __restrict__ bias, float* __restrict__ Y,
    int M, int N, int K)
{
    const int b = blockIdx.z;
    const float* Xb = X + (size_t)b * K * N;
    float* Yb = Y + (size_t)b * M * N;
    const int m0 = blockIdx.y * 64, n0 = blockIdx.x * 64;
    __shared__ float As[16][68];
    __shared__ float Bs[16][64];
    const int tid = threadIdx.x;
    const int tx = tid & 15, ty = tid >> 4;
    float acc[4][4] = {{0.f, 0.f, 0.f, 0.f}, {0.f, 0.f, 0.f, 0.f},
                       {0.f, 0.f, 0.f, 0.f}, {0.f, 0.f, 0.f, 0.f}};
    for (int k0 = 0; k0 < K; k0 += 16) {
        {
            const int m = tid >> 2, kq = (tid & 3) << 2;
            float4 a = *(const float4*)(W + (size_t)(m0 + m) * K + k0 + kq);
            As[kq + 0][m] = a.x; As[kq + 1][m] = a.y;
            As[kq + 2][m] = a.z; As[kq + 3][m] = a.w;
            const int kk = tid >> 4, n4 = (tid & 15) << 2;
            float4 xv = *(const float4*)(Xb + (size_t)(k0 + kk) * N + n0 + n4);
            *(float4*)&Bs[kk][n4] = xv;
        }
        __syncthreads();
        #pragma unroll
        for (int k = 0; k < 16; ++k) {
            const float4 a = *(const float4*)&As[k][ty << 2];
            const float4 b4 = *(const float4*)&Bs[k][tx << 2];
            const float av[4] = {a.x, a.y, a.z, a.w};
            const float bv[4] = {b4.x, b4.y, b4.z, b4.w};
            #pragma unroll
            for (int i = 0; i < 4; ++i)
                #pragma unroll
                for (int j = 0; j < 4; ++j)
                    acc[i][j] += av[i] * bv[j];
        }
        __syncthreads();
    }
    #pragma unroll
    for (int i = 0; i < 4; ++i) {
        const int m = m0 + (ty << 2) + i;
        const float bi = bias[m];
        float4 r;
        r.x = fmaxf(acc[i][0] + bi, 0.f);
        r.y = fmaxf(acc[i][1] + bi, 0.f);
        r.z = fmaxf(acc[i][2] + bi, 0.f);
        r.w = fmaxf(acc[i][3] + bi, 0.f);
        *(float4*)(Yb + (size_t)m * N + n0 + (tx << 2)) = r;
    }
}

// C[r,n] = sum_k A[r,k]*Bt[n,k] + bias1[n] + bias2[n]
// grid: (N/64, M/64), block 256, 4x4 per thread
__global__ __launch_bounds__(256) void gemm_abt_bias(
    const float* __restrict__ A, const float* __restrict__ Bt,
    const float* __restrict__ bias1, const float* __restrict__ bias2,
    float* __restrict__ C, int M, int N, int K)
{
    const int r0 = blockIdx.y * 64, n0 = blockIdx.x * 64;
    __shared__ float As[16][68];
    __shared__ float Bs[16][68];
    const int tid = threadIdx.x;
    const int tx = tid & 15, ty = tid >> 4;
    float acc[4][4] = {{0.f, 0.f, 0.f, 0.f}, {0.f, 0.f, 0.f, 0.f},
                       {0.f, 0.f, 0.f, 0.f}, {0.f, 0.f, 0.f, 0.f}};
    for (int k0 = 0; k0 < K; k0 += 16) {
        {
            const int r = tid >> 2, kq = (tid & 3) << 2;
            float4 a = *(const float4*)(A + (size_t)(r0 + r) * K + k0 + kq);
            As[kq + 0][r] = a.x; As[kq + 1][r] = a.y;
            As[kq + 2][r] = a.z; As[kq + 3][r] = a.w;
            float4 bq = *(const float4*)(Bt + (size_t)(n0 + r) * K + k0 + kq);
            Bs[kq + 0][r] = bq.x; Bs[kq + 1][r] = bq.y;
            Bs[kq + 2][r] = bq.z; Bs[kq + 3][r] = bq.w;
        }
        __syncthreads();
        #pragma unroll
        for (int k = 0; k < 16; ++k) {
            const float4 a = *(const float4*)&As[k][ty << 2];
            const float4 b4 = *(const float4*)&Bs[k][tx << 2];
            const float av[4] = {a.x, a.y, a.z, a.w};
            const float bv[4] = {b4.x, b4.y, b4.z, b4.w};
            #pragma unroll
            for (int i = 0; i < 4; ++i)
                #pragma unroll
                for (int j = 0; j < 4; ++j)
                    acc[i][j] += av[i] * bv[j];
        }
        __syncthreads();
    }
    float bb[4];
    #pragma unroll
    for (int j = 0; j < 4; ++j) {
        const int n = n0 + (tx << 2) + j;
        bb[j] = bias1[n] + bias2[n];
    }
    #pragma unroll
    for (int i = 0; i < 4; ++i) {
        const int r = r0 + (ty << 2) + i;
        float4 v;
        v.x = acc[i][0] + bb[0];
        v.y = acc[i][1] + bb[1];
        v.z = acc[i][2] + bb[2];
        v.w = acc[i][3] + bb[3];
        *(float4*)(C + (size_t)r * N + n0 + (tx << 2)) = v;
    }
}

// Forward LSTM scan, weight-stationary in registers.
// 128 blocks (one batch each) x 512 threads. Thread t owns gate rows (t, t+512)
// as packed-f16 register arrays (128 VGPRs):
//   t in [0,256):   rows t (= i gate of j=t)     and t+512 (= g gate of j=t)
//   t in [256,512): rows t (= f gate of j=t-256) and t+512 (= o gate of j=t-256)
// h lives as packed f16 in 512 B of LDS, broadcast-read by all lanes (same
// address across the wave -> LDS broadcast, no conflicts). Dot products via
// v_dot2_f32_f16 (fp32 accumulate). c-state and output-h stay fp32 in the
// f/o owner's registers; the f16 rounding touches only the recurrence inputs.
__global__ __launch_bounds__(512, 2) void lstm_scan(
    const float* __restrict__ xg, const float* __restrict__ whh,
    float* __restrict__ out)
{
    const int tid = threadIdx.x;
    const int b = blockIdx.x;
    __shared__ half2_t h16[128];     // 256 h values, packed pairs
    __shared__ float ish[256];
    __shared__ float gsh[256];

    // Load this thread's two weight rows into registers as packed f16.
    half2_t wA[128], wB[128];
    {
        const float4* rowA = (const float4*)(whh + (size_t)tid * 256);
        const float4* rowB = (const float4*)(whh + (size_t)(tid + 512) * 256);
        #pragma unroll
        for (int k = 0; k < 64; ++k) {
            float4 a = rowA[k];
            float4 bq = rowB[k];
            wA[2 * k + 0] = half2_t{(_Float16)a.x, (_Float16)a.y};
            wA[2 * k + 1] = half2_t{(_Float16)a.z, (_Float16)a.w};
            wB[2 * k + 0] = half2_t{(_Float16)bq.x, (_Float16)bq.y};
            wB[2 * k + 1] = half2_t{(_Float16)bq.z, (_Float16)bq.w};
        }
    }
    if (tid < 128) h16[tid] = half2_t{(_Float16)0.f, (_Float16)0.f};
    float c_state = 0.f, h_cur = 0.f;
    const float* xgb = xg + (size_t)b * TT * GG;
    float pA = xgb[tid], pB = xgb[tid + 512];
    __syncthreads();

    for (int t = 0; t < TT; ++t) {
        float accA = pA, accB = pB;
        if (t < TT - 1) {  // prefetch next step's xg behind the dot loop
            const int o = (t + 1) * GG;
            pA = xgb[o + tid];
            pB = xgb[o + tid + 512];
        }
        const float4* hp = (const float4*)h16;  // 16B broadcast reads
        #pragma unroll
        for (int kk = 0; kk < 32; ++kk) {
            const float4 hv = hp[kk];
            const half2_t h0 = __builtin_bit_cast(half2_t, hv.x);
            const half2_t h1 = __builtin_bit_cast(half2_t, hv.y);
            const half2_t h2 = __builtin_bit_cast(half2_t, hv.z);
            const half2_t h3 = __builtin_bit_cast(half2_t, hv.w);
            accA = fdot2_(wA[4 * kk + 0], h0, accA);
            accA = fdot2_(wA[4 * kk + 1], h1, accA);
            accA = fdot2_(wA[4 * kk + 2], h2, accA);
            accA = fdot2_(wA[4 * kk + 3], h3, accA);
            accB = fdot2_(wB[4 * kk + 0], h0, accB);
            accB = fdot2_(wB[4 * kk + 1], h1, accB);
            accB = fdot2_(wB[4 * kk + 2], h2, accB);
            accB = fdot2_(wB[4 * kk + 3], h3, accB);
        }
        if (tid < 256) { ish[tid] = accA; gsh[tid] = accB; }
        __syncthreads();
        if (tid >= 256) {
            const int j = tid - 256;
            const float ig = sigf(ish[j]);
            const float gg = tanhf_(gsh[j]);
            const float fg = sigf(accA);
            const float og = sigf(accB);
            c_state = fg * c_state + ig * gg;
            h_cur = og * tanhf_(c_state);
            ((__shared__ _Float16*)h16)[j] = (_Float16)h_cur;
        }
        __syncthreads();
    }
    if (tid >= 256) out[(size_t)b * 512 + (tid - 256)] = h_cur;
}

// Backward-direction LSTM, last output only = FIRST step of the reversed scan
// with h=c=0: gates depend only on seq[:, T-1, :] @ w_ih_b^T + biases.
// grid 128 (one per batch), block 256 (one per hidden unit).
__global__ __launch_bounds__(256) void lstm_back_last(
    const float* __restrict__ y2, const float* __restrict__ wih,
    const float* __restrict__ bih, const float* __restrict__ bhh,
    float* __restrict__ out)
{
    const int b = blockIdx.x;
    const int t = threadIdx.x;
    __shared__ float s[256];
    s[t] = y2[(size_t)b * (HID * TT) + (TT - 1) * HID + t];
    __syncthreads();
    float acc[4];
    #pragma unroll
    for (int q = 0; q < 4; ++q) acc[q] = bih[t + q * 256] + bhh[t + q * 256];
    #pragma unroll
    for (int q = 0; q < 4; ++q) {
        const float* w = wih + (size_t)(t + q * 256) * 256;
        float a = acc[q];
        for (int k = 0; k < 256; k += 4) {
            const float4 w4 = *(const float4*)&w[k];
            const float4 h4 = *(const float4*)&s[k];
            a += w4.x * h4.x; a += w4.y * h4.y;
            a += w4.z * h4.z; a += w4.w * h4.w;
        }
        acc[q] = a;
    }
    const float i = sigf(acc[0]), f = sigf(acc[1]);
    const float g = tanhf_(acc[2]), o = sigf(acc[3]);
    (void)f;  // c_prev = 0, forget path vanishes
    const float c = i * g;
    const float h = o * tanhf_(c);
    out[(size_t)b * 512 + 256 + t] = h;
}

extern "C" void kernel_launch(void* const* d_in, const int* in_sizes, int n_in,
                              void* d_out, int out_size, void* d_ws, size_t ws_size,
                              hipStream_t stream) {
    const float* x      = (const float*)d_in[0];
    const float* w1     = (const float*)d_in[1];
    const float* b1     = (const float*)d_in[2];
    const float* w2     = (const float*)d_in[3];
    const float* b2     = (const float*)d_in[4];
    const float* w_ih_f = (const float*)d_in[5];
    const float* w_hh_f = (const float*)d_in[6];
    const float* b_ih_f = (const float*)d_in[7];
    const float* b_hh_f = (const float*)d_in[8];
    const float* w_ih_b = (const float*)d_in[9];
    // d_in[10] = w_hh_b: provably unused (only first reversed step reaches the output)
    const float* b_ih_b = (const float*)d_in[11];
    const float* b_hh_b = (const float*)d_in[12];
    float* out = (float*)d_out;

    // Workspace layout (floats):
    //   y2 : [0, 16777216)                 67.1 MB  (= seq, reshape is identity)
    //   y1 : [16777216, 33554432)          67.1 MB  (dead after conv2)
    //   xg : [16777216, 83886080)         268.4 MB  (overlays y1)
    float* ws = (float*)d_ws;
    float* y2 = ws;
    float* y1 = ws + (size_t)16777216;
    float* xg = ws + (size_t)16777216;

    // conv1: M=256, N=512, K=512
    wgemm_bias_relu<<<dim3(8, 4, BATCH), 256, 0, stream>>>(w1, x, b1, y1, HID, TT, CIN);
    // conv2: M=256, N=512, K=256
    wgemm_bias_relu<<<dim3(8, 4, BATCH), 256, 0, stream>>>(w2, y1, b2, y2, HID, TT, HID);
    // xg_f = seq @ w_ih_f^T + b_ih_f + b_hh_f : M=65536, N=1024, K=256
    gemm_abt_bias<<<dim3(16, 1024), 256, 0, stream>>>(y2, w_ih_f, b_ih_f, b_hh_f,
                                                      xg, BATCH * TT, GG, HID);
    // forward scan (writes out[:, 0:256))
    lstm_scan<<<128, 512, 0, stream>>>(xg, w_hh_f, out);
    // backward last step (writes out[:, 256:512))
    lstm_back_last<<<BATCH, 256, 0, stream>>>(y2, w_ih_b, b_ih_b, b_hh_b, out);
}

// Round 3
// 2191.693 us; speedup vs baseline: 7.1823x; 1.4802x over previous
//
#include <hip/hip_runtime.h>
#include <math.h>

// Sizes fixed by the problem
#define BATCH 128
#define TT 512      // time steps
#define CIN 512
#define HID 256
#define GG 1024     // 4*HID

typedef _Float16 half2_t __attribute__((ext_vector_type(2)));

__device__ __forceinline__ float sigf(float x) { return 1.f / (1.f + __expf(-x)); }
__device__ __forceinline__ float tanhf_(float x) {
    float a = fabsf(x);
    float e = __expf(-2.f * a);
    float r = (1.f - e) / (1.f + e);
    return copysignf(r, x);
}

// v_dot2_f32_f16: 2-way f16 dot with fp32 accumulate
__device__ __forceinline__ float fdot2_(half2_t a, half2_t b, float c) {
#if __has_builtin(__builtin_amdgcn_fdot2)
    return __builtin_amdgcn_fdot2(a, b, c, false);
#else
    return c + (float)a.x * (float)b.x + (float)a.y * (float)b.y;
#endif
}

// C[b][m,n] = relu( sum_k W[m,k] * X[b][k,n] + bias[m] )
__global__ __launch_bounds__(256) void wgemm_bias_relu(
    const float* __restrict__ W, const float* __restrict__ X,
    const float* __restrict__ bias, float* __restrict__ Y,
    int M, int N, int K)
{
    const int b = blockIdx.z;
    const float* Xb = X + (size_t)b * K * N;
    float* Yb = Y + (size_t)b * M * N;
    const int m0 = blockIdx.y * 64, n0 = blockIdx.x * 64;
    __shared__ float As[16][68];
    __shared__ float Bs[16][64];
    const int tid = threadIdx.x;
    const int tx = tid & 15, ty = tid >> 4;
    float acc[4][4] = {{0.f, 0.f, 0.f, 0.f}, {0.f, 0.f, 0.f, 0.f},
                       {0.f, 0.f, 0.f, 0.f}, {0.f, 0.f, 0.f, 0.f}};
    for (int k0 = 0; k0 < K; k0 += 16) {
        {
            const int m = tid >> 2, kq = (tid & 3) << 2;
            float4 a = *(const float4*)(W + (size_t)(m0 + m) * K + k0 + kq);
            As[kq + 0][m] = a.x; As[kq + 1][m] = a.y;
            As[kq + 2][m] = a.z; As[kq + 3][m] = a.w;
            const int kk = tid >> 4, n4 = (tid & 15) << 2;
            float4 xv = *(const float4*)(Xb + (size_t)(k0 + kk) * N + n0 + n4);
            *(float4*)&Bs[kk][n4] = xv;
        }
        __syncthreads();
        #pragma unroll
        for (int k = 0; k < 16; ++k) {
            const float4 a = *(const float4*)&As[k][ty << 2];
            const float4 b4 = *(const float4*)&Bs[k][tx << 2];
            const float av[4] = {a.x, a.y, a.z, a.w};
            const float bv[4] = {b4.x, b4.y, b4.z, b4.w};
            #pragma unroll
            for (int i = 0; i < 4; ++i)
                #pragma unroll
                for (int j = 0; j < 4; ++j)
                    acc[i][j] += av[i] * bv[j];
        }
        __syncthreads();
    }
    #pragma unroll
    for (int i = 0; i < 4; ++i) {
        const int m = m0 + (ty << 2) + i;
        const float bi = bias[m];
        float4 r;
        r.x = fmaxf(acc[i][0] + bi, 0.f);
        r.y = fmaxf(acc[i][1] + bi, 0.f);
        r.z = fmaxf(acc[i][2] + bi, 0.f);
        r.w = fmaxf(acc[i][3] + bi, 0.f);
        *(float4*)(Yb + (size_t)m * N + n0 + (tx << 2)) = r;
    }
}

// C[r,n] = sum_k A[r,k]*Bt[n,k] + bias1[n] + bias2[n]
__global__ __launch_bounds__(256) void gemm_abt_bias(
    const float* __restrict__ A, const float* __restrict__ Bt,
    const float* __restrict__ bias1, const float* __restrict__ bias2,
    float* __restrict__ C, int M, int N, int K)
{
    const int r0 = blockIdx.y * 64, n0 = blockIdx.x * 64;
    __shared__ float As[16][68];
    __shared__ float Bs[16][68];
    const int tid = threadIdx.x;
    const int tx = tid & 15, ty = tid >> 4;
    float acc[4][4] = {{0.f, 0.f, 0.f, 0.f}, {0.f, 0.f, 0.f, 0.f},
                       {0.f, 0.f, 0.f, 0.f}, {0.f, 0.f, 0.f, 0.f}};
    for (int k0 = 0; k0 < K; k0 += 16) {
        {
            const int r = tid >> 2, kq = (tid & 3) << 2;
            float4 a = *(const float4*)(A + (size_t)(r0 + r) * K + k0 + kq);
            As[kq + 0][r] = a.x; As[kq + 1][r] = a.y;
            As[kq + 2][r] = a.z; As[kq + 3][r] = a.w;
            float4 bq = *(const float4*)(Bt + (size_t)(n0 + r) * K + k0 + kq);
            Bs[kq + 0][r] = bq.x; Bs[kq + 1][r] = bq.y;
            Bs[kq + 2][r] = bq.z; Bs[kq + 3][r] = bq.w;
        }
        __syncthreads();
        #pragma unroll
        for (int k = 0; k < 16; ++k) {
            const float4 a = *(const float4*)&As[k][ty << 2];
            const float4 b4 = *(const float4*)&Bs[k][tx << 2];
            const float av[4] = {a.x, a.y, a.z, a.w};
            const float bv[4] = {b4.x, b4.y, b4.z, b4.w};
            #pragma unroll
            for (int i = 0; i < 4; ++i)
                #pragma unroll
                for (int j = 0; j < 4; ++j)
                    acc[i][j] += av[i] * bv[j];
        }
        __syncthreads();
    }
    float bb[4];
    #pragma unroll
    for (int j = 0; j < 4; ++j) {
        const int n = n0 + (tx << 2) + j;
        bb[j] = bias1[n] + bias2[n];
    }
    #pragma unroll
    for (int i = 0; i < 4; ++i) {
        const int r = r0 + (ty << 2) + i;
        float4 v;
        v.x = acc[i][0] + bb[0];
        v.y = acc[i][1] + bb[1];
        v.z = acc[i][2] + bb[2];
        v.w = acc[i][3] + bb[3];
        *(float4*)(C + (size_t)r * N + n0 + (tx << 2)) = v;
    }
}

// Forward LSTM scan: 2 blocks per batch, weights fully register-resident.
//   block bid < 128:  batch bid,      units [0,128)   ("lo")
//   block bid >= 128: batch bid-128,  units [128,256) ("hi")
// 1024 threads: thread = (row rr = tid>>1 of this block's 512 gate rows,
// K-half = tid&1). Weights: 128 K-elems = 64 half2 VGPRs per thread -> no
// spill at the 128-VGPR/4-wave cap. Partner halves of h are exchanged each
// step through MALL via relaxed agent-scope bypass atomics + per-block flag
// (ordering: __syncthreads drains vmcnt before the flag store).
// 256 blocks x 16 waves x 128 VGPR = exactly 1 block/CU -> all co-resident.
__global__ __launch_bounds__(1024, 4) void lstm_scan2(
    const float* __restrict__ xg, const float* __restrict__ whh,
    float* __restrict__ out, unsigned int* __restrict__ xb,
    int* __restrict__ flags)
{
    const int tid = threadIdx.x;
    const int bid = blockIdx.x;
    const int is_hi = (bid >= 128) ? 1 : 0;
    const int g = is_hi ? bid - 128 : bid;
    const int partner = is_hi ? bid - 128 : bid + 128;
    const int half = tid & 1;          // K-half: k in [128*half, 128*half+128)
    const int rr = tid >> 1;           // local row 0..511
    const int q = rr >> 7;             // gate 0..3 (i,f,g,o)
    const int u = rr & 127;            // local unit
    const int row = q * 256 + is_hi * 128 + u;   // global gate row

    __shared__ unsigned int hsh[128];  // full h, 256 f16 (lo units first)
    __shared__ float ish[128], fsh[128], gsh[128];
    _Float16* hf = (_Float16*)hsh;

    // Weights: 64 half2 VGPRs per thread, statically indexed (must not spill)
    half2_t w[64];
    {
        const float4* wp = (const float4*)(whh + (size_t)row * 256 + half * 128);
        #pragma unroll
        for (int k = 0; k < 32; ++k) {
            float4 a = wp[k];
            w[2 * k + 0] = half2_t{(_Float16)a.x, (_Float16)a.y};
            w[2 * k + 1] = half2_t{(_Float16)a.z, (_Float16)a.w};
        }
    }
    if (tid < 128) hsh[tid] = 0u;
    const float* xgb = xg + (size_t)g * TT * GG;
    float xnext = (half == 0) ? xgb[row] : 0.f;
    float c_state = 0.f, h_keep = 0.f;
    __syncthreads();

    for (int t = 0; t < TT; ++t) {
        const float xv = xnext;
        if (half == 0 && t < TT - 1) xnext = xgb[(size_t)(t + 1) * GG + row];
        float a0 = 0.f, a1 = 0.f, a2 = 0.f, a3 = 0.f;
        const float4* hp = (const float4*)hsh + (half << 4);
        #pragma unroll
        for (int kk = 0; kk < 16; ++kk) {
            const float4 hv = hp[kk];
            const half2_t h0 = __builtin_bit_cast(half2_t, hv.x);
            const half2_t h1 = __builtin_bit_cast(half2_t, hv.y);
            const half2_t h2 = __builtin_bit_cast(half2_t, hv.z);
            const half2_t h3 = __builtin_bit_cast(half2_t, hv.w);
            a0 = fdot2_(w[4 * kk + 0], h0, a0);
            a1 = fdot2_(w[4 * kk + 1], h1, a1);
            a2 = fdot2_(w[4 * kk + 2], h2, a2);
            a3 = fdot2_(w[4 * kk + 3], h3, a3);
        }
        float acc = (a0 + a1) + (a2 + a3) + xv;
        acc += __shfl_xor(acc, 1);     // combine K-halves; both lanes get total
        if (!half) {
            if (q == 0) ish[u] = acc;
            else if (q == 1) fsh[u] = acc;
            else if (q == 2) gsh[u] = acc;
        }
        __syncthreads();               // B1: gates staged; h reads of step t done
        if (!half && q == 3) {         // o-gate owners finish the unit
            const float ig = sigf(ish[u]);
            const float fg = sigf(fsh[u]);
            const float gv = tanhf_(gsh[u]);
            const float og = sigf(acc);
            c_state = fg * c_state + ig * gv;
            h_keep = og * tanhf_(c_state);
            const _Float16 h16v = (_Float16)h_keep;
            hf[is_hi * 128 + u] = h16v;        // own half into LDS
            if (t < TT - 1) {
                // pack pairs (u even carries u,u+1) and bypass-store to MALL
                const float hn = __shfl_down(h_keep, 2);
                if ((u & 1) == 0) {
                    unsigned int v =
                        (unsigned int)__builtin_bit_cast(unsigned short, h16v) |
                        ((unsigned int)__builtin_bit_cast(unsigned short, (_Float16)hn) << 16);
                    unsigned int* dst =
                        xb + (((size_t)g * 2 + (t & 1)) * 2 + is_hi) * 64 + (u >> 1);
                    __hip_atomic_store(dst, v, __ATOMIC_RELAXED, __HIP_MEMORY_SCOPE_AGENT);
                }
            }
        }
        __syncthreads();               // B2: drains all waves' stores (vmcnt)
        if (t < TT - 1) {
            if (tid < 64) {            // wave 0: flag, poll, copy partner half
                if (tid == 0) {
                    __hip_atomic_store(&flags[bid * 32], t + 1,
                                       __ATOMIC_RELAXED, __HIP_MEMORY_SCOPE_AGENT);
                    while (__hip_atomic_load(&flags[partner * 32],
                                             __ATOMIC_RELAXED, __HIP_MEMORY_SCOPE_AGENT) < t + 1)
                        __builtin_amdgcn_s_sleep(1);
                }
                asm volatile("" ::: "memory");  // compiler barrier after poll
                unsigned int* src =
                    xb + (((size_t)g * 2 + (t & 1)) * 2 + (1 - is_hi)) * 64;
                unsigned int v = __hip_atomic_load(&src[tid], __ATOMIC_RELAXED,
                                                   __HIP_MEMORY_SCOPE_AGENT);
                hsh[(1 - is_hi) * 64 + tid] = v;
            }
            __syncthreads();           // B3: partner half visible to all
        }
    }
    if (!half && q == 3) out[(size_t)g * 512 + is_hi * 128 + u] = h_keep;
}

// Backward-direction LSTM, last output only = FIRST step of the reversed scan
// with h=c=0: gates depend only on seq[:, T-1, :] @ w_ih_b^T + biases.
__global__ __launch_bounds__(256) void lstm_back_last(
    const float* __restrict__ y2, const float* __restrict__ wih,
    const float* __restrict__ bih, const float* __restrict__ bhh,
    float* __restrict__ out)
{
    const int b = blockIdx.x;
    const int t = threadIdx.x;
    __shared__ float s[256];
    s[t] = y2[(size_t)b * (HID * TT) + (TT - 1) * HID + t];
    __syncthreads();
    float acc[4];
    #pragma unroll
    for (int q = 0; q < 4; ++q) acc[q] = bih[t + q * 256] + bhh[t + q * 256];
    #pragma unroll
    for (int q = 0; q < 4; ++q) {
        const float* w = wih + (size_t)(t + q * 256) * 256;
        float a = acc[q];
        for (int k = 0; k < 256; k += 4) {
            const float4 w4 = *(const float4*)&w[k];
            const float4 h4 = *(const float4*)&s[k];
            a += w4.x * h4.x; a += w4.y * h4.y;
            a += w4.z * h4.z; a += w4.w * h4.w;
        }
        acc[q] = a;
    }
    const float i = sigf(acc[0]);
    const float g = tanhf_(acc[2]), o = sigf(acc[3]);
    const float c = i * g;           // c_prev = 0, forget path vanishes
    const float h = o * tanhf_(c);
    out[(size_t)b * 512 + 256 + t] = h;
}

extern "C" void kernel_launch(void* const* d_in, const int* in_sizes, int n_in,
                              void* d_out, int out_size, void* d_ws, size_t ws_size,
                              hipStream_t stream) {
    const float* x      = (const float*)d_in[0];
    const float* w1     = (const float*)d_in[1];
    const float* b1     = (const float*)d_in[2];
    const float* w2     = (const float*)d_in[3];
    const float* b2     = (const float*)d_in[4];
    const float* w_ih_f = (const float*)d_in[5];
    const float* w_hh_f = (const float*)d_in[6];
    const float* b_ih_f = (const float*)d_in[7];
    const float* b_hh_f = (const float*)d_in[8];
    const float* w_ih_b = (const float*)d_in[9];
    // d_in[10] = w_hh_b: provably unused (only first reversed step reaches the output)
    const float* b_ih_b = (const float*)d_in[11];
    const float* b_hh_b = (const float*)d_in[12];
    float* out = (float*)d_out;

    // Workspace layout (floats):
    //   y2 : [0, 16777216)                 67.1 MB  (= seq; dead once back_last ran)
    //   y1 : [16777216, 33554432)          67.1 MB  (dead after conv2)
    //   xg : [16777216, 83886080)         268.4 MB  (overlays y1)
    //   flags: y2[0:8192)      32 KB  (padded: 1 flag per 128 B)  } overlay y2,
    //   xbuf : y2[8192:40960) 128 KB  (h-exchange, 2 slots/dir)   } after back_last
    float* ws = (float*)d_ws;
    float* y2 = ws;
    float* y1 = ws + (size_t)16777216;
    float* xg = ws + (size_t)16777216;
    int* flags = (int*)ws;
    unsigned int* xb = (unsigned int*)ws + 8192;

    // conv1: M=256, N=512, K=512
    wgemm_bias_relu<<<dim3(8, 4, BATCH), 256, 0, stream>>>(w1, x, b1, y1, HID, TT, CIN);
    // conv2: M=256, N=512, K=256
    wgemm_bias_relu<<<dim3(8, 4, BATCH), 256, 0, stream>>>(w2, y1, b2, y2, HID, TT, HID);
    // xg_f = seq @ w_ih_f^T + b_ih_f + b_hh_f : M=65536, N=1024, K=256
    gemm_abt_bias<<<dim3(16, 1024), 256, 0, stream>>>(y2, w_ih_f, b_ih_f, b_hh_f,
                                                      xg, BATCH * TT, GG, HID);
    // backward last step first (frees y2 region for the exchange buffers)
    lstm_back_last<<<BATCH, 256, 0, stream>>>(y2, w_ih_b, b_ih_b, b_hh_b, out);
    // zero the handshake flags (harness poisons ws each call)
    hipMemsetAsync(flags, 0, 32768, stream);
    // forward scan (writes out[:, 0:256))
    lstm_scan2<<<256, 1024, 0, stream>>>(xg, w_hh_f, out, xb, flags);
}